// Round 8
// baseline (112.536 us; speedup 1.0000x reference)
//
#include <hip/hip_runtime.h>
#include <hip/hip_bf16.h>
#include <stdint.h>
#include <math.h>

// MMD: N=8192 rows (4096 source + 4096 target), D=256, fp32 in, scalar fp32 out.
// result = (1/4096^2) * sum_ij s_i s_j ksum(L2_ij),  s_i = +1 (i<4096) else -1
// ksum = w + w^2 + w^4 + w^8 + w^16,  w = exp(-L2/(16 bw0))
// bw0 = [2N*sum(sq) - 2*sum_d colsum_d^2] / (N^2-N) / 4  (analytic sum(L2))
// R1: same-address fp64 CAS atomics catastrophic. R2: XOR swizzle for LDS.
// R5 FAILED: per-block agent fences (L2 wb/inv storms). R6 (98us) fp8 splitK.
// R7 FAILED: 2 blk/CU occupancy loss. R8 (94.5us): 3-kernel best.
// R9/R10 FAILED: intra-tile overlap. R11: kconv 512 blocks -> +5.4us.
// R12 (93.9us): MXFP4 whole-K; structure edits move <1us.
// R13 FAILED: cooperative fusion. R14 (127us): ACQ_REL tail -> fence storms.
// R15 (109us): fence-free tail + kconv 1024-thr. MEASURED: kgemm = 42us wall,
//     VALUBusy 20.6%, MfmaUtil 3.4%, Occ 29% -> kgemm is ~40us in ALL rounds
//     and ~15% of its VALU floor; stall is structure-insensitive. Occupancy
//     ceiling is REGISTER-bound: 64 VGPR + 64 AGPR acc = 128 unified ->
//     4 waves/SIMD max for this decomposition. CONFOUND: +15 = kconv-1024
//     regression OR tail cost — cannot split end-to-end.
// R16: deconfound run that is also best-bet: kconv = R12 verbatim (256x256),
//     kgemm = R12 inner + R15 fence-free tail. vs R12 isolates tail;
//     vs R15 isolates kconv-1024.

#define NTOT 8192
#define DDIM 256
#define TILE 128
#define NBLK 2080   // 2016 strict-upper off-diag + 64 diagonal (last)

typedef int i32x8 __attribute__((ext_vector_type(8)));
typedef int i32x4 __attribute__((ext_vector_type(4)));
typedef float f32x4 __attribute__((ext_vector_type(4)));
typedef float f32x2 __attribute__((ext_vector_type(2)));

__device__ __forceinline__ void gl_lds16(const void* g, void* l) {
  __builtin_amdgcn_global_load_lds(
      (const __attribute__((address_space(1))) void*)g,
      (__attribute__((address_space(3))) void*)l, 16, 0, 0);
}

// fp32 -> e2m1 quantize: returns dequant value v and 4-bit code c.
// Self-consistent: v is EXACTLY what the MFMA dequantizes code c to.
__device__ __forceinline__ void q4(float x, float& v, int& c) {
  float a = fabsf(x);
  float av; int m;
  if (a < 0.25f)      { av = 0.0f; m = 0; }
  else if (a < 0.75f) { av = 0.5f; m = 1; }
  else if (a < 1.25f) { av = 1.0f; m = 2; }
  else if (a < 1.75f) { av = 1.5f; m = 3; }
  else if (a < 2.5f)  { av = 2.0f; m = 4; }
  else if (a < 3.5f)  { av = 3.0f; m = 5; }
  else if (a < 5.0f)  { av = 4.0f; m = 6; }
  else                { av = 6.0f; m = 7; }
  v = copysignf(av, x);
  c = ((__float_as_uint(x) >> 31) << 3) | m;
}

// ---- fp32 -> fp4(e2m1) convert + per-row sq + f32-atomic column/sq sums ----
// R12-proven grid: 256 blocks x 256 threads, 32 rows each.
__global__ __launch_bounds__(256) void kconv(const float* __restrict__ src,
                                             const float* __restrict__ tgt,
                                             unsigned char* __restrict__ X4,
                                             float* __restrict__ sq,
                                             float* __restrict__ colsum,   // [256]
                                             float* __restrict__ ssqacc) {
  int b = blockIdx.x;           // 256 blocks, 32 rows each
  int t = threadIdx.x;
  int lane = t & 63, wave = t >> 6;
  float cp0 = 0.f, cp1 = 0.f, cp2 = 0.f, cp3 = 0.f;
  float sqp = 0.f;

  #pragma unroll
  for (int it = 0; it < 8; ++it) {
    int row = b * 32 + it * 4 + wave;
    const float* base = (row < 4096) ? (src + (size_t)row * DDIM)
                                     : (tgt + (size_t)(row - 4096) * DDIM);
    float4 v = ((const float4*)base)[lane];
    float f0, f1, f2, f3; int c0, c1, c2, c3;
    q4(v.x, f0, c0); q4(v.y, f1, c1); q4(v.z, f2, c2); q4(v.w, f3, c3);
    unsigned short pk = (unsigned short)(c0 | (c1 << 4) | (c2 << 8) | (c3 << 12));
    ((unsigned short*)(X4 + (size_t)row * 128))[lane] = pk;
    cp0 += f0; cp1 += f1; cp2 += f2; cp3 += f3;
    float s = f0 * f0 + f1 * f1 + f2 * f2 + f3 * f3;
    #pragma unroll
    for (int off = 32; off; off >>= 1) s += __shfl_down(s, off);
    if (lane == 0) { sq[row] = s; sqp += s; }
  }

  __shared__ float cred[4][256];
  __shared__ float sred[4];
  ((float4*)&cred[wave][lane * 4])[0] = make_float4(cp0, cp1, cp2, cp3);
  if (lane == 0) sred[wave] = sqp;
  __syncthreads();
  float csum = cred[0][t] + cred[1][t] + cred[2][t] + cred[3][t];
  // native f32 relaxed RMW: 256 distinct addresses (no CAS, no hot-spot)
  atomicAdd(&colsum[t], csum);
  if (t == 0) atomicAdd(ssqacc, sred[0] + sred[1] + sred[2] + sred[3]);
}

// ---- main: triangular Gram, MX-fp4 whole-K, 33KB LDS, 4 blk/CU ----
// R12 inner structure verbatim; R15 fence-free last-block-done tail.
__global__ __launch_bounds__(256, 4) void kgemm(const unsigned char* __restrict__ X4,
                                                const float* __restrict__ sq,
                                                const float* __restrict__ colsum,
                                                const float* __restrict__ ssqacc,
                                                unsigned long long* __restrict__ accFx, // [8]
                                                int* __restrict__ cnt8,                 // [8]
                                                int* __restrict__ cntF,                 // [1]
                                                float* __restrict__ out) {
  int b = blockIdx.x;
  int tr, tc;
  if (b < 2016) {  // strict upper: offset(tr) = tr*(127-tr)/2
    tr = (int)((127.0 - sqrt(127.0 * 127.0 - 8.0 * (double)b)) * 0.5);
    while (tr > 0 && tr * (127 - tr) / 2 > b) --tr;
    while ((tr + 1) * (126 - tr) / 2 <= b) ++tr;
    tc = tr + 1 + (b - tr * (127 - tr) / 2);
  } else {
    tr = tc = b - 2016;
  }
  bool diag = (tr == tc);

  __shared__ alignas(16) unsigned char Ash[TILE * 128];  // 16 KB (whole K, fp4)
  __shared__ alignas(16) unsigned char Bsh[TILE * 128];  // 16 KB
  __shared__ float sqR2[TILE], sqC2[TILE];
  __shared__ double red[4];
  __shared__ int lastFlag;

  int t = threadIdx.x;
  int wave = t >> 6, lane = t & 63;
  int mrow = lane & 15, q = lane >> 4;
  int wr = (wave & 1) * 64, wc = (wave >> 1) * 64;
  const int sone = 0x7F7F7F7F;  // e8m0 scale = 1.0

  const unsigned char* Ag = X4 + (size_t)tr * TILE * 128;  // 128 B/row (fp4)
  const unsigned char* Bg = X4 + (size_t)tc * TILE * 128;

  // ---- issue whole-K staging FIRST (bw0 compute hides behind it) ----
  #pragma unroll
  for (int cc = 0; cc < 4; ++cc) {
    int c = t + cc * 256;
    int row = c >> 3, kcs = c & 7;
    int kc = kcs ^ (row & 7);
    gl_lds16(Ag + (size_t)row * 128 + kc * 16, Ash + c * 16);
  }
  if (!diag) {
    #pragma unroll
    for (int cc = 0; cc < 4; ++cc) {
      int c = t + cc * 256;
      int row = c >> 3, kcs = c & 7;
      int kc = kcs ^ (row & 7);
      gl_lds16(Bg + (size_t)row * 128 + kc * 16, Bsh + c * 16);
    }
  }

  // ---- wave-redundant bw0: colsum^2 sum + ssq, 6 shuffle rounds, no LDS ----
  float4 cv = ((const float4*)colsum)[lane];
  float scp = cv.x * cv.x + cv.y * cv.y + cv.z * cv.z + cv.w * cv.w;
  #pragma unroll
  for (int off = 32; off; off >>= 1) scp += __shfl_down(scp, off);
  scp = __shfl(scp, 0);                 // Σ colsum_d^2 (all lanes)
  float ssq = *ssqacc;
  double sumL2 = 2.0 * 8192.0 * (double)ssq - 2.0 * (double)scp;
  double bw0 = sumL2 / (8192.0 * 8192.0 - 8192.0) / 4.0;
  float kk = (float)(-1.44269504088896 / (16.0 * bw0));  // cs * log2(e)

  if (t < 128) sqR2[t] = kk * sq[tr * TILE + t];
  else         sqC2[t - 128] = kk * sq[tc * TILE + (t - 128)];

  f32x4 acc[4][4];
  #pragma unroll
  for (int i = 0; i < 4; ++i)
    #pragma unroll
    for (int j = 0; j < 4; ++j) acc[i][j] = (f32x4){0.f, 0.f, 0.f, 0.f};

  __syncthreads();  // B1: staging + sqR2/sqC2 done (single drain per tile)

  const unsigned char* Bs = diag ? Ash : Bsh;
  int sw = mrow & 7;
  // ---- two K-steps of 128 fp4 elements (64 B/row each), no restage ----
  #pragma unroll
  for (int ks = 0; ks < 2; ++ks) {
    int ks4 = ks * 4;
    i32x8 af[4], bf[4];
    #pragma unroll
    for (int f = 0; f < 4; ++f) {
      int rowA = wr + 16 * f + mrow;
      int rowB = wc + 16 * f + mrow;
      af[f] = (i32x8){0, 0, 0, 0, 0, 0, 0, 0};
      bf[f] = (i32x8){0, 0, 0, 0, 0, 0, 0, 0};
      *(i32x4*)&af[f] = *(const i32x4*)&Ash[rowA * 128 + ((ks4 + q) ^ sw) * 16];
      *(i32x4*)&bf[f] = *(const i32x4*)&Bs[rowB * 128 + ((ks4 + q) ^ sw) * 16];
    }
    #pragma unroll
    for (int fr = 0; fr < 4; ++fr)
      #pragma unroll
      for (int fc = 0; fc < 4; ++fc)
        acc[fr][fc] = __builtin_amdgcn_mfma_scale_f32_16x16x128_f8f6f4(
            af[fr], bf[fc], acc[fr][fc], 4, 4, 0, sone, 0, sone);  // fmt 4 = fp4
  }

  // epilogue: x = -2k*dot + sr + sc; w = exp2(x); ksum = w+w2+w4+w8+w16.
  // C/D layout col=lane&15, row=(lane>>4)*4+reg [m89/m91; dtype-indep]
  float a2s = -2.f * kk;
  f32x2 a2 = {a2s, a2s};
  f32x2 sum2 = {0.f, 0.f};
  int rq = q * 4, cl = mrow;
  #pragma unroll
  for (int fr = 0; fr < 4; ++fr) {
    int rbase = wr + 16 * fr + rq;
    f32x2 sr01 = {sqR2[rbase + 0], sqR2[rbase + 1]};
    f32x2 sr23 = {sqR2[rbase + 2], sqR2[rbase + 3]};
    #pragma unroll
    for (int fc = 0; fc < 4; ++fc) {
      float sc = sqC2[wc + 16 * fc + cl];
      f32x2 scv = {sc, sc};
      f32x2 d01 = {acc[fr][fc][0], acc[fr][fc][1]};
      f32x2 d23 = {acc[fr][fc][2], acc[fr][fc][3]};
      f32x2 x01 = a2 * d01 + (sr01 + scv);
      f32x2 x23 = a2 * d23 + (sr23 + scv);
      f32x2 w01 = {__builtin_amdgcn_exp2f(x01.x), __builtin_amdgcn_exp2f(x01.y)};
      f32x2 w23 = {__builtin_amdgcn_exp2f(x23.x), __builtin_amdgcn_exp2f(x23.y)};
      f32x2 p01 = w01 * w01, p23 = w23 * w23;           // w^2
      f32x2 s01 = w01 + p01, s23 = w23 + p23;
      p01 = p01 * p01; p23 = p23 * p23;                 // w^4
      s01 = s01 + p01; s23 = s23 + p23;
      p01 = p01 * p01; p23 = p23 * p23;                 // w^8
      s01 = s01 + p01; s23 = s23 + p23;
      p01 = p01 * p01; p23 = p23 * p23;                 // w^16
      s01 = s01 + p01; s23 = s23 + p23;
      sum2 = sum2 + (s01 + s23);
    }
  }
  float lsum = sum2.x + sum2.y;

  double wt = diag ? 1.0 : 2.0;
  if ((tr < 32) != (tc < 32)) wt = -wt;  // s_i*s_j uniform per 128-tile
  double ds = (double)lsum * wt;
  #pragma unroll
  for (int off = 32; off; off >>= 1) ds += __shfl_down(ds, off);
  if (lane == 0) red[wave] = ds;
  __syncthreads();  // B2

  // ---- fence-free last-block-done finish: RELAXED RMWs + datadep order ----
  if (t == 0) {
    double bs = red[0] + red[1] + red[2] + red[3];
    // fixed-point 2^20: |bs| <= ~1.7e5 -> scaled <= 1.8e11; sum < 2^63.
    long long fx = llround(bs * 1048576.0);
    unsigned long long oldv =
        atomicAdd(&accFx[b & 7], (unsigned long long)fx);
    // force s_waitcnt on oldv (RMW complete at coherence point) and forbid
    // hoisting the counter RMW above this point:
    asm volatile("" :: "v"(oldv) : "memory");
    int elect = 0;
    int o1 = atomicAdd(&cnt8[b & 7], 1);
    if (o1 == NBLK / 8 - 1) {          // 260 blocks per slot, this is last
      asm volatile("" :: "v"(o1) : "memory");
      int o2 = atomicAdd(cntF, 1);
      elect = (o2 == 7);               // all 8 slots complete
    }
    lastFlag = elect;
  }
  __syncthreads();  // B3

  if (lastFlag) {
    // coherence-point reads of the 8 accumulator slots (relaxed RMW)
    long long v = 0;
    if (t < 8) v = (long long)atomicOr(&accFx[t], 0ULL);
    #pragma unroll
    for (int off = 4; off; off >>= 1) v += __shfl_down(v, off);
    if (t == 0)
      out[0] = (float)(((double)v / 1048576.0) / (4096.0 * 4096.0));
  }
}

extern "C" void kernel_launch(void* const* d_in, const int* in_sizes, int n_in,
                              void* d_out, int out_size, void* d_ws, size_t ws_size,
                              hipStream_t stream) {
  const float* src = (const float*)d_in[0];
  const float* tgt = (const float*)d_in[1];
  char* ws = (char*)d_ws;
  unsigned char* X4 = (unsigned char*)ws;             // 8192*128 = 1 MiB (fp4)
  float* sq      = (float*)(ws + 1048576);            // 32 KiB
  float* colsum  = (float*)(ws + 1081344);            // 256 f
  float* ssqacc  = colsum + 256;                      // +1024
  int*   cnt8    = (int*)(colsum + 257);              // +1028 (32 B)
  int*   cntF    = (int*)(colsum + 265);              // +1060 (4 B)
  unsigned long long* accFx =
      (unsigned long long*)(ws + 1081344 + 1064);     // 8-aligned, 64 B
  float* out = (float*)d_out;

  hipMemsetAsync((void*)colsum, 0, 1152, stream);     // zero all atomic targets
  hipLaunchKernelGGL(kconv, dim3(256), dim3(256), 0, stream,
                     src, tgt, X4, sq, colsum, ssqacc);
  hipLaunchKernelGGL(kgemm, dim3(NBLK), dim3(256), 0, stream,
                     X4, sq, colsum, ssqacc, accFx, cnt8, cntF, out);
}

// Round 9
// 108.633 us; speedup vs baseline: 1.0359x; 1.0359x over previous
//
#include <hip/hip_runtime.h>
#include <hip/hip_bf16.h>
#include <stdint.h>
#include <math.h>

// MMD: N=8192 rows (4096 source + 4096 target), D=256, fp32 in, scalar fp32 out.
// result = (1/4096^2) * sum_ij s_i s_j ksum(L2_ij),  s_i = +1 (i<4096) else -1
// ksum = w + w^2 + w^4 + w^8 + w^16,  w = exp(-L2/(16 bw0))
// bw0 = [2N*sum(sq) - 2*sum_d colsum_d^2] / (N^2-N) / 4  (analytic sum(L2))
// R1: same-address fp64 CAS atomics catastrophic. R2: XOR swizzle for LDS.
// R5 FAILED: per-block agent fences (L2 wb/inv storms). R6 (98us) fp8 splitK.
// R7 FAILED: 2 blk/CU occupancy loss. R8 (94.5us): 3-kernel best.
// R9/R10 FAILED: intra-tile overlap. R11: kconv 512 BLOCKS -> +5.4us (atomic
//     contention scales with block count, not thread count).
// R12 (93.9us): MXFP4 whole-K; intra-tile structure edits move <1us.
// R13 FAILED: cooperative fusion. R14 (127us): ACQ_REL tail -> fence storms.
// R15 (109us)/R16 (112.5us): DECONFOUNDED. Fence-free tail = +18us (2080
//     blocks' counter RMWs serialize on 1-2 cache lines at coherence point).
//     kconv-1024thr better than kconv-256thr by ~3.5us (R15 vs R16 direct).
//     ATOMIC FINISHES DEAD (3 ways). kfin dispatch is the cheap option.
//     kgemm MEASURED 38-42us = 76% of controllable; latency-bound
//     (Occ 29%, VALU 20%, Mfma 3.4%); insensitive to intra-tile edits.
// R17: attack PER-BLOCK overhead: persistent kgemm, grid=1024 (exact 4
//     blk/CU residency). Blocks 0..1007: off-diag tiles {b, b+1008};
//     blocks 1008..1023: 4 diag tiles each (diag ~half cost -> balanced).
//     bw0 once per block; tiles strictly sequential (no overlap - R9/R10);
//     B2 barrier at loop end protects LDS reuse. kfin reduces 1024 partials.
//     kconv = R15's 1024-thread version (256 atomic-ing blocks unchanged).

#define NTOT 8192
#define DDIM 256
#define TILE 128
#define NOFF 1008   // off-diag pairs per persistent block wave
#define GRID 1024

typedef int i32x8 __attribute__((ext_vector_type(8)));
typedef int i32x4 __attribute__((ext_vector_type(4)));
typedef float f32x4 __attribute__((ext_vector_type(4)));
typedef float f32x2 __attribute__((ext_vector_type(2)));

__device__ __forceinline__ void gl_lds16(const void* g, void* l) {
  __builtin_amdgcn_global_load_lds(
      (const __attribute__((address_space(1))) void*)g,
      (__attribute__((address_space(3))) void*)l, 16, 0, 0);
}

// fp32 -> e2m1 quantize: returns dequant value v and 4-bit code c.
// Self-consistent: v is EXACTLY what the MFMA dequantizes code c to.
__device__ __forceinline__ void q4(float x, float& v, int& c) {
  float a = fabsf(x);
  float av; int m;
  if (a < 0.25f)      { av = 0.0f; m = 0; }
  else if (a < 0.75f) { av = 0.5f; m = 1; }
  else if (a < 1.25f) { av = 1.0f; m = 2; }
  else if (a < 1.75f) { av = 1.5f; m = 3; }
  else if (a < 2.5f)  { av = 2.0f; m = 4; }
  else if (a < 3.5f)  { av = 3.0f; m = 5; }
  else if (a < 5.0f)  { av = 4.0f; m = 6; }
  else                { av = 6.0f; m = 7; }
  v = copysignf(av, x);
  c = ((__float_as_uint(x) >> 31) << 3) | m;
}

// ---- fp32 -> fp4(e2m1) convert + per-row sq + f32-atomic column/sq sums ----
// 256 blocks x 1024 threads, 32 rows each (16 waves/CU TLP; 256 atomic-ing
// blocks = proven contention level).
__global__ __launch_bounds__(1024) void kconv(const float* __restrict__ src,
                                              const float* __restrict__ tgt,
                                              unsigned char* __restrict__ X4,
                                              float* __restrict__ sq,
                                              float* __restrict__ colsum,  // [256]
                                              float* __restrict__ ssqacc) {
  int b = blockIdx.x;           // 256 blocks, 32 rows each
  int t = threadIdx.x;          // 0..1023
  int lane = t & 63, wave = t >> 6;   // 16 waves
  float cp0 = 0.f, cp1 = 0.f, cp2 = 0.f, cp3 = 0.f;
  float sqp = 0.f;

  #pragma unroll
  for (int it = 0; it < 2; ++it) {
    int row = b * 32 + it * 16 + wave;
    const float* base = (row < 4096) ? (src + (size_t)row * DDIM)
                                     : (tgt + (size_t)(row - 4096) * DDIM);
    float4 v = ((const float4*)base)[lane];
    float f0, f1, f2, f3; int c0, c1, c2, c3;
    q4(v.x, f0, c0); q4(v.y, f1, c1); q4(v.z, f2, c2); q4(v.w, f3, c3);
    unsigned short pk = (unsigned short)(c0 | (c1 << 4) | (c2 << 8) | (c3 << 12));
    ((unsigned short*)(X4 + (size_t)row * 128))[lane] = pk;
    cp0 += f0; cp1 += f1; cp2 += f2; cp3 += f3;
    float s = f0 * f0 + f1 * f1 + f2 * f2 + f3 * f3;
    #pragma unroll
    for (int off = 32; off; off >>= 1) s += __shfl_down(s, off);
    if (lane == 0) { sq[row] = s; sqp += s; }
  }

  __shared__ float cred[16][256];   // 16 KB
  __shared__ float sred[16];
  ((float4*)&cred[wave][lane * 4])[0] = make_float4(cp0, cp1, cp2, cp3);
  if (lane == 0) sred[wave] = sqp;
  __syncthreads();
  if (t < 256) {
    float csum = 0.f;
    #pragma unroll
    for (int w = 0; w < 16; ++w) csum += cred[w][t];
    atomicAdd(&colsum[t], csum);
  }
  if (t == 0) {
    float s2 = 0.f;
    #pragma unroll
    for (int w = 0; w < 16; ++w) s2 += sred[w];
    atomicAdd(ssqacc, s2);
  }
}

// ---- main: persistent triangular Gram, MX-fp4 whole-K, 33KB LDS, 4 blk/CU --
// grid=1024 co-resident. Per block: 2 off-diag tiles or 4 diag tiles,
// strictly sequential; bw0 computed once; Spart[b] written once.
__global__ __launch_bounds__(256, 4) void kgemm(const unsigned char* __restrict__ X4,
                                                const float* __restrict__ sq,
                                                const float* __restrict__ colsum,
                                                const float* __restrict__ ssqacc,
                                                double* __restrict__ Spart) {
  int b = blockIdx.x;
  int t = threadIdx.x;
  int wave = t >> 6, lane = t & 63;
  int mrow = lane & 15, q = lane >> 4;
  int wr = (wave & 1) * 64, wc = (wave >> 1) * 64;
  const int sone = 0x7F7F7F7F;  // e8m0 scale = 1.0
  int sw = mrow & 7;

  __shared__ alignas(16) unsigned char Ash[TILE * 128];  // 16 KB (whole K, fp4)
  __shared__ alignas(16) unsigned char Bsh[TILE * 128];  // 16 KB
  __shared__ float sqR2[TILE], sqC2[TILE];
  __shared__ double red[4];

  // ---- wave-redundant bw0 ONCE per block (overlaps nothing yet; cheap) ----
  float4 cv = ((const float4*)colsum)[lane];
  float scp = cv.x * cv.x + cv.y * cv.y + cv.z * cv.z + cv.w * cv.w;
  #pragma unroll
  for (int off = 32; off; off >>= 1) scp += __shfl_down(scp, off);
  scp = __shfl(scp, 0);                 // Σ colsum_d^2 (all lanes)
  float ssq = *ssqacc;
  double sumL2 = 2.0 * 8192.0 * (double)ssq - 2.0 * (double)scp;
  double bw0 = sumL2 / (8192.0 * 8192.0 - 8192.0) / 4.0;
  float kk = (float)(-1.44269504088896 / (16.0 * bw0));  // cs * log2(e)
  float a2s = -2.f * kk;

  int ntile = (b < NOFF) ? 2 : 4;
  double accS = 0.0;

  for (int it = 0; it < ntile; ++it) {
    int tile = (b < NOFF) ? (b + it * NOFF) : (2016 + (b - NOFF) * 4 + it);
    int tr, tc;
    if (tile < 2016) {  // strict upper: offset(tr) = tr*(127-tr)/2
      tr = (int)((127.0 - sqrt(127.0 * 127.0 - 8.0 * (double)tile)) * 0.5);
      while (tr > 0 && tr * (127 - tr) / 2 > tile) --tr;
      while ((tr + 1) * (126 - tr) / 2 <= tile) ++tr;
      tc = tr + 1 + (tile - tr * (127 - tr) / 2);
    } else {
      tr = tc = tile - 2016;
    }
    bool diag = (tr == tc);

    const unsigned char* Ag = X4 + (size_t)tr * TILE * 128;  // 128 B/row (fp4)
    const unsigned char* Bg = X4 + (size_t)tc * TILE * 128;

    // stage whole-K (XOR chunk swizzle): 16B x 4/thread per matrix
    #pragma unroll
    for (int cc = 0; cc < 4; ++cc) {
      int c = t + cc * 256;
      int row = c >> 3, kcs = c & 7;
      int kc = kcs ^ (row & 7);
      gl_lds16(Ag + (size_t)row * 128 + kc * 16, Ash + c * 16);
    }
    if (!diag) {
      #pragma unroll
      for (int cc = 0; cc < 4; ++cc) {
        int c = t + cc * 256;
        int row = c >> 3, kcs = c & 7;
        int kc = kcs ^ (row & 7);
        gl_lds16(Bg + (size_t)row * 128 + kc * 16, Bsh + c * 16);
      }
    }
    if (t < 128) sqR2[t] = kk * sq[tr * TILE + t];
    else         sqC2[t - 128] = kk * sq[tc * TILE + (t - 128)];

    f32x4 acc[4][4];
    #pragma unroll
    for (int i = 0; i < 4; ++i)
      #pragma unroll
      for (int j = 0; j < 4; ++j) acc[i][j] = (f32x4){0.f, 0.f, 0.f, 0.f};

    __syncthreads();  // B1: staging + sqR2/sqC2 done (single drain per tile)

    const unsigned char* Bs = diag ? Ash : Bsh;
    #pragma unroll
    for (int ks = 0; ks < 2; ++ks) {
      int ks4 = ks * 4;
      i32x8 af[4], bf[4];
      #pragma unroll
      for (int f = 0; f < 4; ++f) {
        int rowA = wr + 16 * f + mrow;
        int rowB = wc + 16 * f + mrow;
        af[f] = (i32x8){0, 0, 0, 0, 0, 0, 0, 0};
        bf[f] = (i32x8){0, 0, 0, 0, 0, 0, 0, 0};
        *(i32x4*)&af[f] = *(const i32x4*)&Ash[rowA * 128 + ((ks4 + q) ^ sw) * 16];
        *(i32x4*)&bf[f] = *(const i32x4*)&Bs[rowB * 128 + ((ks4 + q) ^ sw) * 16];
      }
      #pragma unroll
      for (int fr = 0; fr < 4; ++fr)
        #pragma unroll
        for (int fc = 0; fc < 4; ++fc)
          acc[fr][fc] = __builtin_amdgcn_mfma_scale_f32_16x16x128_f8f6f4(
              af[fr], bf[fc], acc[fr][fc], 4, 4, 0, sone, 0, sone);  // fmt4=fp4
    }

    // epilogue: x = -2k*dot + sr + sc; w = exp2(x); ksum = w+w2+w4+w8+w16.
    // C/D layout col=lane&15, row=(lane>>4)*4+reg [m89/m91; dtype-indep]
    f32x2 a2 = {a2s, a2s};
    f32x2 sum2 = {0.f, 0.f};
    int rq = q * 4, cl = mrow;
    #pragma unroll
    for (int fr = 0; fr < 4; ++fr) {
      int rbase = wr + 16 * fr + rq;
      f32x2 sr01 = {sqR2[rbase + 0], sqR2[rbase + 1]};
      f32x2 sr23 = {sqR2[rbase + 2], sqR2[rbase + 3]};
      #pragma unroll
      for (int fc = 0; fc < 4; ++fc) {
        float sc = sqC2[wc + 16 * fc + cl];
        f32x2 scv = {sc, sc};
        f32x2 d01 = {acc[fr][fc][0], acc[fr][fc][1]};
        f32x2 d23 = {acc[fr][fc][2], acc[fr][fc][3]};
        f32x2 x01 = a2 * d01 + (sr01 + scv);
        f32x2 x23 = a2 * d23 + (sr23 + scv);
        f32x2 w01 = {__builtin_amdgcn_exp2f(x01.x), __builtin_amdgcn_exp2f(x01.y)};
        f32x2 w23 = {__builtin_amdgcn_exp2f(x23.x), __builtin_amdgcn_exp2f(x23.y)};
        f32x2 p01 = w01 * w01, p23 = w23 * w23;           // w^2
        f32x2 s01 = w01 + p01, s23 = w23 + p23;
        p01 = p01 * p01; p23 = p23 * p23;                 // w^4
        s01 = s01 + p01; s23 = s23 + p23;
        p01 = p01 * p01; p23 = p23 * p23;                 // w^8
        s01 = s01 + p01; s23 = s23 + p23;
        p01 = p01 * p01; p23 = p23 * p23;                 // w^16
        s01 = s01 + p01; s23 = s23 + p23;
        sum2 = sum2 + (s01 + s23);
      }
    }
    float lsum = sum2.x + sum2.y;

    double wt = diag ? 1.0 : 2.0;
    if ((tr < 32) != (tc < 32)) wt = -wt;  // s_i*s_j uniform per 128-tile
    double ds = (double)lsum * wt;
    #pragma unroll
    for (int off = 32; off; off >>= 1) ds += __shfl_down(ds, off);
    if (lane == 0) red[wave] = ds;
    __syncthreads();  // B2: red ready AND all LDS reads done -> safe restage
    if (t == 0) accS += red[0] + red[1] + red[2] + red[3];
  }

  if (t == 0) Spart[b] = accS;
}

// ---- final reduce of 1024 per-block partials ----
__global__ __launch_bounds__(256) void kfin(const double* __restrict__ Spart,
                                            float* __restrict__ out) {
  int t = threadIdx.x;
  double s = Spart[t] + Spart[t + 256] + Spart[t + 512] + Spart[t + 768];
  __shared__ double red[256];
  red[t] = s;
  __syncthreads();
  for (int off = 128; off; off >>= 1) {
    if (t < off) red[t] += red[t + off];
    __syncthreads();
  }
  if (t == 0) out[0] = (float)(red[0] / (4096.0 * 4096.0));
}

extern "C" void kernel_launch(void* const* d_in, const int* in_sizes, int n_in,
                              void* d_out, int out_size, void* d_ws, size_t ws_size,
                              hipStream_t stream) {
  const float* src = (const float*)d_in[0];
  const float* tgt = (const float*)d_in[1];
  char* ws = (char*)d_ws;
  unsigned char* X4 = (unsigned char*)ws;             // 8192*128 = 1 MiB (fp4)
  float* sq      = (float*)(ws + 1048576);            // 32 KiB
  float* colsum  = (float*)(ws + 1081344);            // 256 f + 1 f (ssq)
  float* ssqacc  = colsum + 256;
  double* Spart  = (double*)(ws + 1083392);           // 8 KiB
  float* out = (float*)d_out;

  hipMemsetAsync((void*)colsum, 0, 1040, stream);     // zero atomic targets
  hipLaunchKernelGGL(kconv, dim3(256), dim3(1024), 0, stream,
                     src, tgt, X4, sq, colsum, ssqacc);
  hipLaunchKernelGGL(kgemm, dim3(GRID), dim3(256), 0, stream,
                     X4, sq, colsum, ssqacc, Spart);
  hipLaunchKernelGGL(kfin, dim3(1), dim3(256), 0, stream, Spart, out);
}

// Round 10
// 93.887 us; speedup vs baseline: 1.1986x; 1.1571x over previous
//
#include <hip/hip_runtime.h>
#include <hip/hip_bf16.h>
#include <stdint.h>
#include <math.h>

// MMD: N=8192 rows (4096 source + 4096 target), D=256, fp32 in, scalar fp32 out.
// result = (1/4096^2) * sum_ij s_i s_j ksum(L2_ij),  s_i = +1 (i<4096) else -1
// ksum = w + w^2 + w^4 + w^8 + w^16,  w = exp(-L2/(16 bw0))
// bw0 = [2N*sum(sq) - 2*sum_d colsum_d^2] / (N^2-N) / 4  (analytic sum(L2))
// R1: same-address fp64 CAS atomics catastrophic. R2: XOR swizzle for LDS.
// R5 FAILED: agent fences. R6 (98us) fp8 splitK. R7 FAILED: occupancy loss.
// R8 (94.5us). R9/R10 FAILED: intra-tile overlap. R11: 512-blk kconv +5.4us.
// R12 (93.9us BEST): MXFP4 whole-K; intra-tile edits move <1us.
// R13 FAILED: cooperative. R14 (127us): ACQ_REL fence storms.
// R15/R16: fence-free atomic tail = +18us (counter RMW serialization).
//     ATOMIC FINISHES DEAD. R17 (108us): persistent kgemm null (+L2 thrash).
// DIAGNOSIS (R17 counters): kgemm 42-43us with VALUBusy 19%, MfmaUtil 3.4%,
//     Occupancy 29% (~2.4 waves/SIMD avg). VALU-busy time ~8us => 80% stall,
//     LATENCY/OCCUPANCY-BOUND. Cause: 128 regs/wave (64 VGPR + 64 acc AGPR)
//     -> 4 waves/SIMD hard cap. Schedule edits can't fix; only TLP can.
// R18: same tile/staging/math, 512-thread blocks (8 waves), per-wave output
//     64x32 -> acc 32 regs/wave (was 64), af transient. launch_bounds(512,6)
//     targets <=85 VGPR -> 24 waves/CU (+50%); if <=64 -> 32 waves/CU (2x).
//     kconv/kfin = R12 exact.

#define NTOT 8192
#define DDIM 256
#define TILE 128
#define NBLK 2080   // 2016 strict-upper off-diag + 64 diagonal (last)

typedef int i32x8 __attribute__((ext_vector_type(8)));
typedef int i32x4 __attribute__((ext_vector_type(4)));
typedef float f32x4 __attribute__((ext_vector_type(4)));

__device__ __forceinline__ void gl_lds16(const void* g, void* l) {
  __builtin_amdgcn_global_load_lds(
      (const __attribute__((address_space(1))) void*)g,
      (__attribute__((address_space(3))) void*)l, 16, 0, 0);
}

// fp32 -> e2m1 quantize: returns dequant value v and 4-bit code c.
// Self-consistent: v is EXACTLY what the MFMA dequantizes code c to.
__device__ __forceinline__ void q4(float x, float& v, int& c) {
  float a = fabsf(x);
  float av; int m;
  if (a < 0.25f)      { av = 0.0f; m = 0; }
  else if (a < 0.75f) { av = 0.5f; m = 1; }
  else if (a < 1.25f) { av = 1.0f; m = 2; }
  else if (a < 1.75f) { av = 1.5f; m = 3; }
  else if (a < 2.5f)  { av = 2.0f; m = 4; }
  else if (a < 3.5f)  { av = 3.0f; m = 5; }
  else if (a < 5.0f)  { av = 4.0f; m = 6; }
  else                { av = 6.0f; m = 7; }
  v = copysignf(av, x);
  c = ((__float_as_uint(x) >> 31) << 3) | m;
}

// ---- fp32 -> fp4(e2m1) convert + per-row sq + f32-atomic column/sq sums ----
// R12 exact: 256 blocks x 256 threads, 32 rows each.
__global__ __launch_bounds__(256) void kconv(const float* __restrict__ src,
                                             const float* __restrict__ tgt,
                                             unsigned char* __restrict__ X4,
                                             float* __restrict__ sq,
                                             float* __restrict__ colsum,   // [256]
                                             float* __restrict__ ssqacc) {
  int b = blockIdx.x;           // 256 blocks, 32 rows each
  int t = threadIdx.x;
  int lane = t & 63, wave = t >> 6;
  float cp0 = 0.f, cp1 = 0.f, cp2 = 0.f, cp3 = 0.f;
  float sqp = 0.f;

  #pragma unroll
  for (int it = 0; it < 8; ++it) {
    int row = b * 32 + it * 4 + wave;
    const float* base = (row < 4096) ? (src + (size_t)row * DDIM)
                                     : (tgt + (size_t)(row - 4096) * DDIM);
    float4 v = ((const float4*)base)[lane];
    float f0, f1, f2, f3; int c0, c1, c2, c3;
    q4(v.x, f0, c0); q4(v.y, f1, c1); q4(v.z, f2, c2); q4(v.w, f3, c3);
    unsigned short pk = (unsigned short)(c0 | (c1 << 4) | (c2 << 8) | (c3 << 12));
    ((unsigned short*)(X4 + (size_t)row * 128))[lane] = pk;
    cp0 += f0; cp1 += f1; cp2 += f2; cp3 += f3;
    float s = f0 * f0 + f1 * f1 + f2 * f2 + f3 * f3;
    #pragma unroll
    for (int off = 32; off; off >>= 1) s += __shfl_down(s, off);
    if (lane == 0) { sq[row] = s; sqp += s; }
  }

  __shared__ float cred[4][256];
  __shared__ float sred[4];
  ((float4*)&cred[wave][lane * 4])[0] = make_float4(cp0, cp1, cp2, cp3);
  if (lane == 0) sred[wave] = sqp;
  __syncthreads();
  float csum = cred[0][t] + cred[1][t] + cred[2][t] + cred[3][t];
  // native f32 relaxed RMW: 256 distinct addresses (no CAS, no hot-spot)
  atomicAdd(&colsum[t], csum);
  if (t == 0) atomicAdd(ssqacc, sred[0] + sred[1] + sred[2] + sred[3]);
}

// ---- main: triangular Gram, MX-fp4 whole-K, 33KB LDS, 512-thr/8-wave ----
// Per wave: 64x32 output (4 rowfrags x 2 colfrags) -> acc = 32 regs/wave.
// Target: >=24 waves/CU (vs 16 at the old 64-reg acc footprint).
__global__ __launch_bounds__(512, 6) void kgemm(const unsigned char* __restrict__ X4,
                                                const float* __restrict__ sq,
                                                const float* __restrict__ colsum,
                                                const float* __restrict__ ssqacc,
                                                double* __restrict__ Spart) {
  int b = blockIdx.x;
  int tr, tc;
  if (b < 2016) {  // strict upper: offset(tr) = tr*(127-tr)/2
    tr = (int)((127.0 - sqrt(127.0 * 127.0 - 8.0 * (double)b)) * 0.5);
    while (tr > 0 && tr * (127 - tr) / 2 > b) --tr;
    while ((tr + 1) * (126 - tr) / 2 <= b) ++tr;
    tc = tr + 1 + (b - tr * (127 - tr) / 2);
  } else {
    tr = tc = b - 2016;
  }
  bool diag = (tr == tc);

  __shared__ alignas(16) unsigned char Ash[TILE * 128];  // 16 KB (whole K, fp4)
  __shared__ alignas(16) unsigned char Bsh[TILE * 128];  // 16 KB
  __shared__ float sqR2[TILE], sqC2[TILE];
  __shared__ double red[8];

  int t = threadIdx.x;            // 0..511
  int wave = t >> 6, lane = t & 63;
  int mrow = lane & 15, q = lane >> 4;
  int sw = mrow & 7;
  int wrh = (wave >> 2) * 64;     // 0 or 64   (row half)
  int wcp = (wave & 3) * 32;      // 0,32,64,96 (col strip)
  const int sone = 0x7F7F7F7F;    // e8m0 scale = 1.0

  const unsigned char* Ag = X4 + (size_t)tr * TILE * 128;  // 128 B/row (fp4)
  const unsigned char* Bg = X4 + (size_t)tc * TILE * 128;

  // ---- issue whole-K staging FIRST (bw0 compute hides behind it) ----
  // 1024 16B-chunks per matrix; 2 per thread; XOR swizzle within row.
  #pragma unroll
  for (int cc = 0; cc < 2; ++cc) {
    int c = t + cc * 512;
    int row = c >> 3, kcs = c & 7;
    int kc = kcs ^ (row & 7);
    gl_lds16(Ag + (size_t)row * 128 + kc * 16, Ash + c * 16);
  }
  if (!diag) {
    #pragma unroll
    for (int cc = 0; cc < 2; ++cc) {
      int c = t + cc * 512;
      int row = c >> 3, kcs = c & 7;
      int kc = kcs ^ (row & 7);
      gl_lds16(Bg + (size_t)row * 128 + kc * 16, Bsh + c * 16);
    }
  }

  // ---- wave-redundant bw0: colsum^2 sum + ssq, 6 shuffle rounds, no LDS ----
  float4 cv = ((const float4*)colsum)[lane];
  float scp = cv.x * cv.x + cv.y * cv.y + cv.z * cv.z + cv.w * cv.w;
  #pragma unroll
  for (int off = 32; off; off >>= 1) scp += __shfl_down(scp, off);
  scp = __shfl(scp, 0);                 // Σ colsum_d^2 (all lanes)
  float ssq = *ssqacc;
  double sumL2 = 2.0 * 8192.0 * (double)ssq - 2.0 * (double)scp;
  double bw0 = sumL2 / (8192.0 * 8192.0 - 8192.0) / 4.0;
  float kk = (float)(-1.44269504088896 / (16.0 * bw0));  // cs * log2(e)
  float a2s = -2.f * kk;

  if (t < 128) sqR2[t] = kk * sq[tr * TILE + t];
  else if (t < 256) sqC2[t - 128] = kk * sq[tc * TILE + (t - 128)];

  f32x4 acc[4][2];
  #pragma unroll
  for (int i = 0; i < 4; ++i)
    #pragma unroll
    for (int j = 0; j < 2; ++j) acc[i][j] = (f32x4){0.f, 0.f, 0.f, 0.f};

  __syncthreads();  // B1: staging + sqR2/sqC2 done (single drain per tile)

  const unsigned char* Bs = diag ? Ash : Bsh;
  // ---- two K-steps of 128 fp4 elements; af transient (register-lean) ----
  #pragma unroll
  for (int ks = 0; ks < 2; ++ks) {
    int kcsel = ((ks * 4 + q) ^ sw) * 16;
    i32x8 bf0 = (i32x8){0, 0, 0, 0, 0, 0, 0, 0};
    i32x8 bf1 = (i32x8){0, 0, 0, 0, 0, 0, 0, 0};
    *(i32x4*)&bf0 = *(const i32x4*)&Bs[(wcp + mrow) * 128 + kcsel];
    *(i32x4*)&bf1 = *(const i32x4*)&Bs[(wcp + 16 + mrow) * 128 + kcsel];
    #pragma unroll
    for (int rf = 0; rf < 4; ++rf) {
      i32x8 af = (i32x8){0, 0, 0, 0, 0, 0, 0, 0};
      *(i32x4*)&af = *(const i32x4*)&Ash[(wrh + rf * 16 + mrow) * 128 + kcsel];
      acc[rf][0] = __builtin_amdgcn_mfma_scale_f32_16x16x128_f8f6f4(
          af, bf0, acc[rf][0], 4, 4, 0, sone, 0, sone);  // fmt 4 = fp4
      acc[rf][1] = __builtin_amdgcn_mfma_scale_f32_16x16x128_f8f6f4(
          af, bf1, acc[rf][1], 4, 4, 0, sone, 0, sone);
    }
  }

  // epilogue: x = -2k*dot + sr + sc; w = exp2(x); ksum = w+w2+w4+w8+w16.
  // C/D layout col=lane&15, row=(lane>>4)*4+reg [m89/m91; dtype-indep]
  float lsum = 0.f;
  int rq = q * 4, cl = mrow;
  #pragma unroll
  for (int rf = 0; rf < 4; ++rf) {
    int rbase = wrh + rf * 16 + rq;
    float sr0 = sqR2[rbase + 0], sr1 = sqR2[rbase + 1];
    float sr2 = sqR2[rbase + 2], sr3 = sqR2[rbase + 3];
    #pragma unroll
    for (int cf = 0; cf < 2; ++cf) {
      float sc = sqC2[wcp + cf * 16 + cl];
      #pragma unroll
      for (int j = 0; j < 4; ++j) {
        float srj = (j == 0) ? sr0 : (j == 1) ? sr1 : (j == 2) ? sr2 : sr3;
        float x = fmaf(a2s, acc[rf][cf][j], srj + sc);
        float w = __builtin_amdgcn_exp2f(x);
        float w2 = w * w, w4 = w2 * w2, w8 = w4 * w4;
        lsum += ((w + w2) + (w4 + w8)) + w8 * w8;   // w+w2+w4+w8+w16
      }
    }
  }

  double wt = diag ? 1.0 : 2.0;
  if ((tr < 32) != (tc < 32)) wt = -wt;  // s_i*s_j uniform per 128-tile
  double ds = (double)lsum * wt;
  #pragma unroll
  for (int off = 32; off; off >>= 1) ds += __shfl_down(ds, off);
  if (lane == 0) red[wave] = ds;
  __syncthreads();  // B2
  if (t == 0) {
    double s = 0.0;
    #pragma unroll
    for (int w = 0; w < 8; ++w) s += red[w];
    Spart[b] = s;
  }
}

// ---- final reduce of 2080 per-block partials ----
__global__ __launch_bounds__(256) void kfin(const double* __restrict__ Spart,
                                            float* __restrict__ out) {
  int t = threadIdx.x;
  double s = 0.0;
  #pragma unroll
  for (int i = 0; i < 9; ++i) {
    int idx = t + i * 256;
    if (idx < NBLK) s += Spart[idx];
  }
  __shared__ double red[256];
  red[t] = s;
  __syncthreads();
  for (int off = 128; off; off >>= 1) {
    if (t < off) red[t] += red[t + off];
    __syncthreads();
  }
  if (t == 0) out[0] = (float)(red[0] / (4096.0 * 4096.0));
}

extern "C" void kernel_launch(void* const* d_in, const int* in_sizes, int n_in,
                              void* d_out, int out_size, void* d_ws, size_t ws_size,
                              hipStream_t stream) {
  const float* src = (const float*)d_in[0];
  const float* tgt = (const float*)d_in[1];
  char* ws = (char*)d_ws;
  unsigned char* X4 = (unsigned char*)ws;             // 8192*128 = 1 MiB (fp4)
  float* sq      = (float*)(ws + 1048576);            // 32 KiB
  float* colsum  = (float*)(ws + 1081344);            // 256 f + 1 f (ssq)
  float* ssqacc  = colsum + 256;
  double* Spart  = (double*)(ws + 1083392);           // 16.25 KiB
  float* out = (float*)d_out;

  hipMemsetAsync((void*)colsum, 0, 1040, stream);     // zero atomic targets
  hipLaunchKernelGGL(kconv, dim3(256), dim3(256), 0, stream,
                     src, tgt, X4, sq, colsum, ssqacc);
  hipLaunchKernelGGL(kgemm, dim3(NBLK), dim3(512), 0, stream,
                     X4, sq, colsum, ssqacc, Spart);
  hipLaunchKernelGGL(kfin, dim3(1), dim3(256), 0, stream, Spart, out);
}